// Round 4
// baseline (156.546 us; speedup 1.0000x reference)
//
#include <hip/hip_runtime.h>
#include <hip/hip_bf16.h>
#include <stdint.h>

typedef __attribute__((ext_vector_type(8))) short bf16x8;
typedef __attribute__((ext_vector_type(4))) float f32x4;
typedef __attribute__((ext_vector_type(4))) unsigned short u16x4;

__device__ __forceinline__ float silu_f(float x) {
    return x * __builtin_amdgcn_rcpf(1.0f + __expf(-x));
}

// round-to-nearest-even f32 -> bf16
__device__ __forceinline__ unsigned short f2bf(float x) {
    union { float f; unsigned int u; } v; v.f = x;
    unsigned int r = v.u + 0x7fffu + ((v.u >> 16) & 1u);
    return (unsigned short)(r >> 16);
}
__device__ __forceinline__ float bf2f(unsigned short u) {
    union { unsigned int u; float f; } v; v.u = ((unsigned int)u) << 16;
    return v.f;
}

// async global->LDS, 16B per lane. LDS dest = wave-uniform base + lane*16.
__device__ __forceinline__ void async16(void* l, const void* g) {
    auto lds3 = (__attribute__((address_space(3))) unsigned int*)(uintptr_t)l;
    auto g1   = (const __attribute__((address_space(1))) unsigned int*)(uintptr_t)g;
    __builtin_amdgcn_global_load_lds(g1, lds3, 16, 0, 0);
}

// Precompute:
//   P1[t][o] = sum_k table[t][k] * W[k][o]       + b[o]   (bf16)
//   P2[t][o] = sum_k table[t][k] * W[128+k][o]            (bf16)
//   Wt3[o][k] = W[256+k][o]                               (bf16, transposed)
__global__ void prep_P(const int* __restrict__ code_idx,
                       const float* __restrict__ codebook,
                       const float* __restrict__ W,
                       const float* __restrict__ b,
                       unsigned short* __restrict__ P1,
                       unsigned short* __restrict__ P2,
                       unsigned short* __restrict__ Wt3)
{
    __shared__ float trow[128];
    const int t = blockIdx.x, tid = threadIdx.x;
    if (tid < 128) {
        int sym = code_idx[t * 8 + (tid >> 4)];
        trow[tid] = codebook[sym * 16 + (tid & 15)];
    } else {
        int k = tid - 128;                       // 0..127
        Wt3[t * 128 + k] = f2bf(W[(256 + k) * 128 + t]);
    }
    __syncthreads();
    const int which = tid >> 7, o = tid & 127;
    const float* Wb = W + which * 16384;
    float acc = which ? 0.0f : b[o];
#pragma unroll 8
    for (int k = 0; k < 128; ++k)
        acc += trow[k] * Wb[k * 128 + o];
    (which ? P2 : P1)[t * 128 + o] = f2bf(acc);
}

// Fused main, 64 edges per block, 256 threads (4 waves, 32x64 C^T-tile each).
// Round-4 structure: NO LDS staging of Wt3. Each wave's 16 B-fragments
// (16 x bf16x8 = 64 VGPR) are loaded DIRECTLY from global (Wt3 is 32KB,
// permanently L2/L3-resident) right after phase 1 -- this deletes the
// 2048 LDS-DMA ops + vmcnt drain + 16 ds_read_b128/wave of the lB path
// and shrinks LDS to 19.4KB. Grid stays at nE/64 = 2500 blocks: round-3
// showed block-level parallelism (not per-block amortization) is what
// hides the serial chain (everything <30% utilized = latency-bound).
//   lR = rbf tile (64 x 24B), async16-staged
//   lA = r = silu(rbf @ W_rbf + b_rbf) bf16, VALU-computed, XOR-swizzled
//   C^T = B @ A^T via SWAPPED mfma operands: each lane owns one edge x 4
//   consecutive output cols per tile -> float4 stores, ushort4 P-gathers.
//   Stores PLAIN (cached): output fits L3; NT stores = round-1 regression.
__global__ __launch_bounds__(256, 3) void fused_main(
    const int* __restrict__ x,
    const float* __restrict__ rbf,
    const int* __restrict__ ei,
    const int* __restrict__ ej,
    const float* __restrict__ W_rbf,
    const float* __restrict__ b_rbf,
    const unsigned short* __restrict__ P1,
    const unsigned short* __restrict__ P2,
    const unsigned short* __restrict__ Wt3,
    float* __restrict__ out)
{
    __shared__ __align__(16) unsigned char lA[16384];  // r [64 rows][256B]
    __shared__ __align__(16) unsigned char lR[1536];   // rbf [64 rows][24B]

    const int tid  = threadIdx.x;
    const int lane = tid & 63;
    const int w    = tid >> 6;
    const int e0   = blockIdx.x * 64;

    const int quad = lane >> 4, l15 = lane & 15;
    const int wm = (w >> 1) * 32, wn = (w & 1) * 64;

    // ---- phase 0: lR async stage + index chase + r-weights ----
    if (w == 0)
        async16(lR, (const unsigned char*)rbf + (size_t)e0 * 24 + lane * 16);
    else if (w == 1 && lane < 32)
        async16(lR + 1024, (const unsigned char*)rbf + (size_t)e0 * 24 + 1024 + lane * 16);

    // epilogue row indices: lane (l15) owns edge wm+mi*16+l15 (same for all
    // quads) -> only 2 chases per thread per table
    int ti[2], tj[2];
#pragma unroll
    for (int mi = 0; mi < 2; ++mi) {
        int e = e0 + wm + mi * 16 + l15;
        ti[mi] = x[ei[e]];
        tj[mi] = x[ej[e]];
    }

    // r-weights (L2-hot, identical for all blocks); dead after phase 1
    const int j16 = tid & 15, gg = tid >> 4, cb = j16 * 8;
    float wr[6][8], br[8];
#pragma unroll
    for (int q = 0; q < 6; ++q) {
        const float4* p = (const float4*)(W_rbf + q * 128 + cb);
        float4 a = p[0], c = p[1];
        wr[q][0]=a.x; wr[q][1]=a.y; wr[q][2]=a.z; wr[q][3]=a.w;
        wr[q][4]=c.x; wr[q][5]=c.y; wr[q][6]=c.z; wr[q][7]=c.w;
    }
    {
        const float4* p = (const float4*)(b_rbf + cb);
        float4 a = p[0], c = p[1];
        br[0]=a.x; br[1]=a.y; br[2]=a.z; br[3]=a.w;
        br[4]=c.x; br[5]=c.y; br[6]=c.z; br[7]=c.w;
    }

    __syncthreads();   // drains async16 (rbf tile in LDS)

    // ---- phase 1: r-compute from lR -> lA (4 edges x 8 cols per thread) ----
#pragma unroll
    for (int i = 0; i < 4; ++i) {
        int m = gg * 4 + i;
        const float* rr_ = (const float*)(lR + m * 24);
        float f0 = rr_[0], f1 = rr_[1], f2 = rr_[2],
              f3 = rr_[3], f4 = rr_[4], f5 = rr_[5];
        bf16x8 pk;
#pragma unroll
        for (int c = 0; c < 8; ++c) {
            float a = br[c] + f0*wr[0][c] + f1*wr[1][c] + f2*wr[2][c]
                            + f3*wr[3][c] + f4*wr[4][c] + f5*wr[5][c];
            pk[c] = (short)f2bf(silu_f(a));
        }
        int p = j16 ^ (m & 7);
        *(bf16x8*)(lA + m * 256 + p * 16) = pk;
    }

    // ---- B fragments: direct from global (L2-hot), issued pre-barrier so
    // latency hides under the barrier + P-gathers. [ni][ks], 64 VGPR.
    bf16x8 Bf[4][4];
#pragma unroll
    for (int ni = 0; ni < 4; ++ni) {
        const unsigned short* brow = Wt3 + (wn + ni * 16 + l15) * 128 + quad * 8;
#pragma unroll
        for (int ks = 0; ks < 4; ++ks)
            Bf[ni][ks] = *(const bf16x8*)(brow + ks * 32);
    }

    // P prefetch (ushort4; L2-hot)
    u16x4 q1[2][4], q2[2][4];
#pragma unroll
    for (int mi = 0; mi < 2; ++mi) {
        const unsigned short* p1r = P1 + ti[mi] * 128;
        const unsigned short* p2r = P2 + tj[mi] * 128;
#pragma unroll
        for (int ni = 0; ni < 4; ++ni) {
            int o = wn + ni * 16 + quad * 4;
            q1[mi][ni] = *(const u16x4*)(p1r + o);
            q2[mi][ni] = *(const u16x4*)(p2r + o);
        }
    }

    __syncthreads();   // lA ready

    // ---- phase 2: MFMA (A from lA, B from registers) ----
    f32x4 acc[2][4] = {};
    const int l7 = l15 & 7;
#pragma unroll
    for (int ks = 0; ks < 4; ++ks) {
        const int j = ks * 4 + quad;
        const int p = j ^ l7;
        bf16x8 af[2];
#pragma unroll
        for (int mi = 0; mi < 2; ++mi)
            af[mi] = *(const bf16x8*)(lA + (wm + mi * 16 + l15) * 256 + p * 16);
        // swapped operands: D = Wt3_tile . r_tile^T = C^T
        // lane: col = l15 = edge, rows = quad*4+reg = 4 consecutive o
#pragma unroll
        for (int mi = 0; mi < 2; ++mi)
#pragma unroll
            for (int ni = 0; ni < 4; ++ni)
                acc[mi][ni] = __builtin_amdgcn_mfma_f32_16x16x32_bf16(
                    Bf[ni][ks], af[mi], acc[mi][ni], 0, 0, 0);
    }

    // ---- phase 3: epilogue — one edge/lane, float4 cached stores ----
#pragma unroll
    for (int mi = 0; mi < 2; ++mi) {
        size_t e = (size_t)(e0 + wm + mi * 16 + l15);
        float* orow = out + e * 128 + wn;
#pragma unroll
        for (int ni = 0; ni < 4; ++ni) {
            f32x4 v;
#pragma unroll
            for (int r = 0; r < 4; ++r)
                v[r] = silu_f(acc[mi][ni][r]
                              + bf2f(q1[mi][ni][r]) + bf2f(q2[mi][ni][r]));
            *(f32x4*)(orow + ni * 16 + quad * 4) = v;
        }
    }
}

extern "C" void kernel_launch(void* const* d_in, const int* in_sizes, int n_in,
                              void* d_out, int out_size, void* d_ws, size_t ws_size,
                              hipStream_t stream) {
    const int*   x        = (const int*)d_in[0];
    const float* rbf      = (const float*)d_in[1];
    const int*   ei       = (const int*)d_in[2];
    const int*   ej       = (const int*)d_in[3];
    const int*   code_idx = (const int*)d_in[4];
    const float* codebook = (const float*)d_in[5];
    const float* W_rbf    = (const float*)d_in[6];
    const float* b_rbf    = (const float*)d_in[7];
    const float* W        = (const float*)d_in[8];
    const float* b        = (const float*)d_in[9];
    float* out = (float*)d_out;

    const int nE = in_sizes[2];                   // 160000

    if (ws_size < 98304) return;                  // P1 + P2 + Wt3, bf16
    unsigned short* P1  = (unsigned short*)d_ws;  // 32 KB
    unsigned short* P2  = P1 + 16384;             // 32 KB
    unsigned short* Wt3 = P2 + 16384;             // 32 KB

    prep_P<<<128, 256, 0, stream>>>(code_idx, codebook, W, b, P1, P2, Wt3);
    fused_main<<<nE / 64, 256, 0, stream>>>(x, rbf, ei, ej, W_rbf, b_rbf,
                                            P1, P2, Wt3, out);
}

// Round 5
// 152.788 us; speedup vs baseline: 1.0246x; 1.0246x over previous
//
#include <hip/hip_runtime.h>
#include <hip/hip_bf16.h>
#include <stdint.h>

typedef __attribute__((ext_vector_type(8))) short bf16x8;
typedef __attribute__((ext_vector_type(4))) float f32x4;
typedef __attribute__((ext_vector_type(4))) unsigned short u16x4;

__device__ __forceinline__ float silu_f(float x) {
    return x * __builtin_amdgcn_rcpf(1.0f + __expf(-x));
}

// round-to-nearest-even f32 -> bf16
__device__ __forceinline__ unsigned short f2bf(float x) {
    union { float f; unsigned int u; } v; v.f = x;
    unsigned int r = v.u + 0x7fffu + ((v.u >> 16) & 1u);
    return (unsigned short)(r >> 16);
}
__device__ __forceinline__ float bf2f(unsigned short u) {
    union { unsigned int u; float f; } v; v.u = ((unsigned int)u) << 16;
    return v.f;
}

// async global->LDS, 16B per lane. LDS dest = wave-uniform base + lane*16.
__device__ __forceinline__ void async16(void* l, const void* g) {
    auto lds3 = (__attribute__((address_space(3))) unsigned int*)(uintptr_t)l;
    auto g1   = (const __attribute__((address_space(1))) unsigned int*)(uintptr_t)g;
    __builtin_amdgcn_global_load_lds(g1, lds3, 16, 0, 0);
}

// Precompute:
//   P1[t][o] = sum_k table[t][k] * W[k][o]       + b[o]   (bf16)
//   P2[t][o] = sum_k table[t][k] * W[128+k][o]            (bf16)
//   Wt3[o][k] = W[256+k][o]                               (bf16, transposed)
__global__ void prep_P(const int* __restrict__ code_idx,
                       const float* __restrict__ codebook,
                       const float* __restrict__ W,
                       const float* __restrict__ b,
                       unsigned short* __restrict__ P1,
                       unsigned short* __restrict__ P2,
                       unsigned short* __restrict__ Wt3)
{
    __shared__ float trow[128];
    const int t = blockIdx.x, tid = threadIdx.x;
    if (tid < 128) {
        int sym = code_idx[t * 8 + (tid >> 4)];
        trow[tid] = codebook[sym * 16 + (tid & 15)];
    } else {
        int k = tid - 128;                       // 0..127
        Wt3[t * 128 + k] = f2bf(W[(256 + k) * 128 + t]);
    }
    __syncthreads();
    const int which = tid >> 7, o = tid & 127;
    const float* Wb = W + which * 16384;
    float acc = which ? 0.0f : b[o];
#pragma unroll 8
    for (int k = 0; k < 128; ++k)
        acc += trow[k] * Wb[k * 128 + o];
    (which ? P2 : P1)[t * 128 + o] = f2bf(acc);
}

// Fused main, 64 edges per block, 512 threads = 8 waves.
// Round-5 structure: same per-block WORK as the best (round-2) version but
// spread over 8 waves instead of 4 -- each wave owns a 16x64 C^T-tile
// (16 MFMA, 8 P-gathers, 4 stores, 1 chase pair). Rationale: round-4's
// traffic-free rocprof replay had IDENTICAL duration (58us) to the
// 1.4TB/s replay => kernel is pure latency-bound; avg resident waves were
// only ~8/CU with blocks living ~12us for ~2us of work. Doubling
// waves/block doubles both in-block parallelism and the per-CU wave pool
// (LDS 50.7KB -> 3 blocks/CU = 24 waves static ceiling).
//   lB = Wt3 (128x128 bf16), async16-staged, chunk-swizzled (B from LDS:
//        round-4's direct-global B was 6us slower than the LDS path).
//   lR = rbf tile (64 x 24B), async16-staged
//   lA = r = silu(rbf @ W_rbf + b_rbf) bf16, VALU-computed, XOR-swizzled
//   C^T = B @ A^T via SWAPPED mfma operands: each lane owns one edge x 4
//   consecutive output cols per tile -> float4 stores, ushort4 P-gathers.
//   Stores PLAIN (cached): NT stores = round-1 regression.
__global__ __launch_bounds__(512, 6) void fused_main(
    const int* __restrict__ x,
    const float* __restrict__ rbf,
    const int* __restrict__ ei,
    const int* __restrict__ ej,
    const float* __restrict__ W_rbf,
    const float* __restrict__ b_rbf,
    const unsigned short* __restrict__ P1,
    const unsigned short* __restrict__ P2,
    const unsigned short* __restrict__ Wt3,
    float* __restrict__ out)
{
    __shared__ __align__(16) unsigned char lB[32768];  // Wt3 [128 rows][256B]
    __shared__ __align__(16) unsigned char lA[16384];  // r   [64 rows][256B]
    __shared__ __align__(16) unsigned char lR[1536];   // rbf [64 rows][24B]

    const int tid  = threadIdx.x;
    const int lane = tid & 63;
    const int w    = tid >> 6;          // 0..7
    const int e0   = blockIdx.x * 64;

    const int quad = lane >> 4, l15 = lane & 15, l7 = l15 & 7;
    const int wm = (w >> 1) * 16;       // 16-edge row group
    const int wn = (w & 1) * 64;        // 64-col half

    // ---- phase 0: async stages + index chase ----
    {   // B: physical chunk ch holds logical chunk ch ^ (o&7)
        const int ri = lane >> 4, ch = lane & 15;
#pragma unroll
        for (int rr = 0; rr < 4; ++rr) {
            int g = w * 4 + rr;           // 4-row group 0..31
            int o = g * 4 + ri;
            int jc = ch ^ (o & 7);
            async16(lB + g * 1024, Wt3 + o * 128 + jc * 8);
        }
    }
    // rbf tile: 1536B contiguous
    if (w == 0)
        async16(lR, (const unsigned char*)rbf + (size_t)e0 * 24 + lane * 16);
    else if (w == 1 && lane < 32)
        async16(lR + 1024, (const unsigned char*)rbf + (size_t)e0 * 24 + 1024 + lane * 16);

    // epilogue row index: lane (l15) owns edge wm+l15; chase now, use after
    // phase 1 (plenty of slack to cover the dependent L2 round trips)
    int ti, tj;
    {
        int e = e0 + wm + l15;
        ti = x[ei[e]];
        tj = x[ej[e]];
    }

    // r-weights (L2-hot, identical for all blocks); dead after phase 1
    const int j16 = tid & 15, gg = tid >> 4, cb = j16 * 8;
    float wr[6][8], br[8];
#pragma unroll
    for (int q = 0; q < 6; ++q) {
        const float4* p = (const float4*)(W_rbf + q * 128 + cb);
        float4 a = p[0], c = p[1];
        wr[q][0]=a.x; wr[q][1]=a.y; wr[q][2]=a.z; wr[q][3]=a.w;
        wr[q][4]=c.x; wr[q][5]=c.y; wr[q][6]=c.z; wr[q][7]=c.w;
    }
    {
        const float4* p = (const float4*)(b_rbf + cb);
        float4 a = p[0], c = p[1];
        br[0]=a.x; br[1]=a.y; br[2]=a.z; br[3]=a.w;
        br[4]=c.x; br[5]=c.y; br[6]=c.z; br[7]=c.w;
    }

    __syncthreads();   // drains async16 (B + rbf in LDS)

    // ---- phase 1: r-compute from lR -> lA (2 edges x 8 cols per thread) ----
#pragma unroll
    for (int i = 0; i < 2; ++i) {
        int m = gg * 2 + i;
        const float* rr_ = (const float*)(lR + m * 24);
        float f0 = rr_[0], f1 = rr_[1], f2 = rr_[2],
              f3 = rr_[3], f4 = rr_[4], f5 = rr_[5];
        bf16x8 pk;
#pragma unroll
        for (int c = 0; c < 8; ++c) {
            float a = br[c] + f0*wr[0][c] + f1*wr[1][c] + f2*wr[2][c]
                            + f3*wr[3][c] + f4*wr[4][c] + f5*wr[5][c];
            pk[c] = (short)f2bf(silu_f(a));
        }
        int p = j16 ^ (m & 7);
        *(bf16x8*)(lA + m * 256 + p * 16) = pk;
    }

    // P prefetch (ushort4; L2-hot) -- overlaps the barrier + LDS reads
    u16x4 q1[4], q2[4];
#pragma unroll
    for (int ni = 0; ni < 4; ++ni) {
        int o = wn + ni * 16 + quad * 4;
        q1[ni] = *(const u16x4*)(P1 + ti * 128 + o);
        q2[ni] = *(const u16x4*)(P2 + tj * 128 + o);
    }

    __syncthreads();   // lA ready

    // ---- phase 2: register-hoist fragments, then 16 back-to-back MFMA ----
    bf16x8 Bf[4][4];   // [ni][ks]
#pragma unroll
    for (int ni = 0; ni < 4; ++ni) {
        const unsigned char* brow = lB + (wn + ni * 16 + l15) * 256;
#pragma unroll
        for (int ks = 0; ks < 4; ++ks)
            Bf[ni][ks] = *(const bf16x8*)(brow + (((ks * 4 + quad) ^ l7) * 16));
    }
    bf16x8 af[4];
    {
        const unsigned char* arow = lA + (wm + l15) * 256;
#pragma unroll
        for (int ks = 0; ks < 4; ++ks)
            af[ks] = *(const bf16x8*)(arow + (((ks * 4 + quad) ^ l7) * 16));
    }

    f32x4 acc[4] = {};
#pragma unroll
    for (int ks = 0; ks < 4; ++ks)
#pragma unroll
        for (int ni = 0; ni < 4; ++ni)
            acc[ni] = __builtin_amdgcn_mfma_f32_16x16x32_bf16(
                Bf[ni][ks], af[ks], acc[ni], 0, 0, 0);

    // ---- phase 3: epilogue — one edge/lane, float4 cached stores ----
    {
        size_t e = (size_t)(e0 + wm + l15);
        float* orow = out + e * 128 + wn;
#pragma unroll
        for (int ni = 0; ni < 4; ++ni) {
            f32x4 v;
#pragma unroll
            for (int r = 0; r < 4; ++r)
                v[r] = silu_f(acc[ni][r] + bf2f(q1[ni][r]) + bf2f(q2[ni][r]));
            *(f32x4*)(orow + ni * 16 + quad * 4) = v;
        }
    }
}

extern "C" void kernel_launch(void* const* d_in, const int* in_sizes, int n_in,
                              void* d_out, int out_size, void* d_ws, size_t ws_size,
                              hipStream_t stream) {
    const int*   x        = (const int*)d_in[0];
    const float* rbf      = (const float*)d_in[1];
    const int*   ei       = (const int*)d_in[2];
    const int*   ej       = (const int*)d_in[3];
    const int*   code_idx = (const int*)d_in[4];
    const float* codebook = (const float*)d_in[5];
    const float* W_rbf    = (const float*)d_in[6];
    const float* b_rbf    = (const float*)d_in[7];
    const float* W        = (const float*)d_in[8];
    const float* b        = (const float*)d_in[9];
    float* out = (float*)d_out;

    const int nE = in_sizes[2];                   // 160000

    if (ws_size < 98304) return;                  // P1 + P2 + Wt3, bf16
    unsigned short* P1  = (unsigned short*)d_ws;  // 32 KB
    unsigned short* P2  = P1 + 16384;             // 32 KB
    unsigned short* Wt3 = P2 + 16384;             // 32 KB

    prep_P<<<128, 256, 0, stream>>>(code_idx, codebook, W, b, P1, P2, Wt3);
    fused_main<<<nE / 64, 512, 0, stream>>>(x, rbf, ei, ej, W_rbf, b_rbf,
                                            P1, P2, Wt3, out);
}